// Round 1
// baseline (900.844 us; speedup 1.0000x reference)
//
#include <hip/hip_runtime.h>
#include <hip/hip_bf16.h>

// Problem constants
#define BB 32
#define LQ 18
#define LK 4096
#define DD 768
#define SCALE 0.03608439182435161f  // 1/sqrt(768)

// Workspace layout (bytes):
//   P       : [32][18][4096] fp32   @ 0        (9,437,184 B)
//   partial : [32][18][64]   fp32   @ 9437184  (147,456 B)  per-wave denom partials
//   wqd     : [32][18]       fp32   @ 9584640  (2,304 B)    W[q]/denom[b][q]
//   flag    : int                   @ 9586944  (4 B)        mask dtype: 1=int32, 0=byte
#define WS_P       0
#define WS_PARTIAL 9437184
#define WS_WQD     9584640
#define WS_FLAG    9586944

// K-tile geometry for LDS staging
#define DK 32            // d-tile width in floats (128 B per row)
#define NT (DD / DK)     // 24 tiles

// async global->LDS, 16B per lane; LDS dest is linear (base + lane*16),
// so the bank-conflict swizzle is applied to the *global source* address
// and mirrored on the LDS read side (both-sides-or-neither rule).
#define GLD16(gp, lp) __builtin_amdgcn_global_load_lds(                      \
    (const __attribute__((address_space(1))) void*)(gp),                     \
    (__attribute__((address_space(3))) void*)(lp), 16, 0, 0)

// ---------------------------------------------------------------------------
// Mask dtype detection (unchanged): deterministic, graph-capture safe.
__global__ void detect_kernel(const unsigned char* __restrict__ m,
                              int* __restrict__ flag) {
    __shared__ int cnt;
    if (threadIdx.x == 0) cnt = 0;
    __syncthreads();
    int c = 0;
    for (int i = threadIdx.x; i < 16384; i += 256) {
        if ((i & 3) != 0 && m[i] != 0) c = 1;
    }
    if (c) atomicAdd(&cnt, 1);
    __syncthreads();
    if (threadIdx.x == 0) *flag = (cnt == 0) ? 1 : 0;
}

// ---------------------------------------------------------------------------
// Kernel 1: scores + masked exp + per-wave denominator partials.
// Thread t owns K row (chunk*256+t). K is staged through LDS in 256x32-float
// tiles via global_load_lds (coalesced 128B-line fetches), double-buffered
// with raw s_barrier + counted vmcnt so tile t+1 streams under compute of t.
// XOR swizzle (c ^= row&7) applied on the global source and on the LDS read
// breaks the stride-128B bank conflict on ds_read_b128.
__global__ __launch_bounds__(256, 2) void qk_softmax_kernel(
    const float* __restrict__ Qg, const float* __restrict__ Kg,
    const void* __restrict__ maskg, const int* __restrict__ flag,
    float* __restrict__ P, float* __restrict__ partial) {
    const int chunk = blockIdx.x;   // 0..15
    const int b     = blockIdx.y;   // 0..31
    const int tid   = threadIdx.x;
    const int k     = chunk * 256 + tid;

    __shared__ float kt[2][256 * DK];   // 2 x 32 KiB

    const float* Kb = Kg + ((size_t)b * LK + (size_t)chunk * 256) * DD;
    const float* Qb = Qg + (size_t)b * LQ * DD;

    float acc[LQ];
#pragma unroll
    for (int q = 0; q < LQ; ++q) acc[q] = 0.0f;

    // Stage one 256x32-float K tile: slot s = i*256+tid -> (row=s>>3, c=s&7),
    // LDS dest linear at s*16B, global src col-group pre-swizzled.
    auto stage = [&](float* dst, int d0) {
#pragma unroll
        for (int i = 0; i < 8; ++i) {
            const int s   = i * 256 + tid;
            const int row = s >> 3;
            const int c   = s & 7;
            const float* src = Kb + (size_t)row * DD + d0 + ((c ^ (row & 7)) << 2);
            GLD16(src, dst + s * 4);
        }
    };

    stage(kt[0], 0);                      // prologue: tile 0 in flight (8 loads)

    const int sw = tid & 7;

    for (int t = 0; t < NT; ++t) {
        float* buf = kt[t & 1];
        if (t + 1 < NT) {
            stage(kt[(t + 1) & 1], (t + 1) * DK);            // 16 in flight
            asm volatile("s_waitcnt vmcnt(8)" ::: "memory"); // tile t landed (ours)
        } else {
            asm volatile("s_waitcnt vmcnt(0)" ::: "memory");
        }
        __builtin_amdgcn_s_barrier();            // all waves' tile-t loads done
        asm volatile("" ::: "memory");

        // read own row (tid) of the tile: 8 x ds_read_b128, swizzled
        float4 kv[8];
#pragma unroll
        for (int c = 0; c < 8; ++c)
            kv[c] = *(const float4*)(buf + tid * DK + ((c ^ sw) << 2));

        const int d0 = t * DK;
#pragma unroll
        for (int q = 0; q < LQ; ++q) {
            const float* Qr = Qb + q * DD + d0;   // wave-uniform -> s_load
#pragma unroll
            for (int c = 0; c < 8; ++c) {
                const float4 qv = *(const float4*)(Qr + (c << 2));
                acc[q] += qv.x * kv[c].x;
                acc[q] += qv.y * kv[c].y;
                acc[q] += qv.z * kv[c].z;
                acc[q] += qv.w * kv[c].w;
            }
        }
        // drain own LDS reads before signaling buffer free (next stage
        // overwrites this buffer right after the barrier)
        asm volatile("s_waitcnt lgkmcnt(0)" ::: "memory");
        __builtin_amdgcn_s_barrier();
        asm volatile("" ::: "memory");
    }

    const int isI32 = *flag;
    const unsigned char* m8  = (const unsigned char*)maskg;
    const int*           m32 = (const int*)maskg;

    float p[LQ];
#pragma unroll
    for (int q = 0; q < LQ; ++q) {
        const size_t idx = ((size_t)b * LQ + q) * LK + k;
        const int msk = isI32 ? m32[idx] : (int)m8[idx];
        const float pv = msk ? 0.0f : __expf(acc[q] * SCALE);
        p[q] = pv;
        P[idx] = pv;
    }

    // wave-level reduction of denominator partials (deterministic, no atomics)
    const int lane = tid & 63;
    const int wv   = tid >> 6;  // 0..3
#pragma unroll
    for (int q = 0; q < LQ; ++q) {
        float s = p[q];
#pragma unroll
        for (int off = 32; off > 0; off >>= 1) s += __shfl_xor(s, off, 64);
        if (lane == 0)
            partial[((size_t)b * LQ + q) * 64 + (chunk * 4 + wv)] = s;
    }
}

// ---------------------------------------------------------------------------
// Kernel 2: reduce 64 per-wave partials -> wqd[b][q] = W[q]/denom[b][q]
__global__ void denom_kernel(const float* __restrict__ partial,
                             const float* __restrict__ Wg,
                             float* __restrict__ wqd) {
    const int b = blockIdx.x;
    const int q = threadIdx.x;
    if (q < LQ) {
        const float* pp = partial + ((size_t)b * LQ + q) * 64;
        float s = 0.0f;
#pragma unroll
        for (int w = 0; w < 64; ++w) s += pp[w];
        wqd[b * LQ + q] = Wg[q] / s;
    }
}

// ---------------------------------------------------------------------------
// Kernel 3: attn_fc[b,k] = sum_q P[b,q,k]*wqd[b,q]; context[b,d] += af*V[b,k,d]
// Phase A: thread t <-> row k0+t (coalesced P reads), af -> LDS + d_out.
// Phase B: 192 lanes x float4 over d (one full 3KB V row per instruction).
__global__ __launch_bounds__(256, 2) void fc_context_kernel(
    const float* __restrict__ P, const float* __restrict__ Vg,
    const float* __restrict__ wqd, float* __restrict__ ctx_out,
    float* __restrict__ af_out) {
    const int chunk = blockIdx.x;   // 0..15
    const int b     = blockIdx.y;
    const int tid   = threadIdx.x;
    const int k0    = chunk * 256;

    __shared__ float af_s[256];

    {
        const int k = k0 + tid;
        float af = 0.0f;
#pragma unroll
        for (int q = 0; q < LQ; ++q) {
            af += P[((size_t)b * LQ + q) * LK + k] * wqd[b * LQ + q];
        }
        af_s[tid] = af;
        af_out[(size_t)b * LK + k] = af;
    }
    __syncthreads();

    if (tid < 192) {
        const int d = tid << 2;                 // 0..764, float4 per lane
        const float* Vb = Vg + ((size_t)b * LK + k0) * DD + d;
        float cx = 0.0f, cy = 0.0f, cz = 0.0f, cw = 0.0f;
#pragma unroll 8
        for (int j = 0; j < 256; ++j) {
            const float  a = af_s[j];
            const float4 v = *(const float4*)(Vb + (size_t)j * DD);
            cx += a * v.x;
            cy += a * v.y;
            cz += a * v.z;
            cw += a * v.w;
        }
        float* cp = ctx_out + b * DD + d;
        atomicAdd(cp + 0, cx);
        atomicAdd(cp + 1, cy);
        atomicAdd(cp + 2, cz);
        atomicAdd(cp + 3, cw);
    }
}

// ---------------------------------------------------------------------------
extern "C" void kernel_launch(void* const* d_in, const int* in_sizes, int n_in,
                              void* d_out, int out_size, void* d_ws, size_t ws_size,
                              hipStream_t stream) {
    const float* Qg   = (const float*)d_in[0];
    const float* Kg   = (const float*)d_in[1];
    const float* Vg   = (const float*)d_in[2];
    const void*  mask = d_in[3];
    const float* Wg   = (const float*)d_in[4];

    // outputs: context [32,1,768] then attn_fc [32,4096,1], both fp32
    float* ctx_out = (float*)d_out;
    float* af_out  = (float*)d_out + BB * DD;

    char*  ws      = (char*)d_ws;
    float* P       = (float*)(ws + WS_P);
    float* partial = (float*)(ws + WS_PARTIAL);
    float* wqd     = (float*)(ws + WS_WQD);
    int*   flag    = (int*)(ws + WS_FLAG);

    // context region accumulated via atomics -> zero it (memset node is
    // graph-capture safe). attn_fc region is fully overwritten, no memset.
    hipMemsetAsync(d_out, 0, BB * DD * sizeof(float), stream);

    detect_kernel<<<1, 256, 0, stream>>>((const unsigned char*)mask, flag);
    qk_softmax_kernel<<<dim3(16, BB), 256, 0, stream>>>(Qg, Kg, mask, flag, P, partial);
    denom_kernel<<<BB, 64, 0, stream>>>(partial, Wg, wqd);
    fc_context_kernel<<<dim3(16, BB), 256, 0, stream>>>(P, Vg, wqd, ctx_out, af_out);
}

// Round 3
// 854.760 us; speedup vs baseline: 1.0539x; 1.0539x over previous
//
#include <hip/hip_runtime.h>
#include <hip/hip_bf16.h>

// Problem constants
#define BB 32
#define LQ 18
#define LK 4096
#define DD 768
#define SCALE 0.03608439182435161f  // 1/sqrt(768)

// Workspace layout (bytes):
//   P       : [32][18][4096] fp32   @ 0        (9,437,184 B)
//   partial : [32][18][32]   fp32   @ 9437184  (73,728 B)   per-block denom partials
//   wqd     : [32][18]       fp32   @ 9510912  (2,304 B)    W[q]/denom[b][q]
//   flag    : int                   @ 9513216  (4 B)        mask dtype: 1=int32, 0=byte
#define WS_P       0
#define WS_PARTIAL 9437184
#define WS_WQD     9510912
#define WS_FLAG    9513216

// async global->LDS, 16B per lane (LDS dest = uniform base + lane*16, linear)
#define GLD16(gp, lp) __builtin_amdgcn_global_load_lds(                      \
    (const __attribute__((address_space(1))) void*)(gp),                     \
    (__attribute__((address_space(3))) void*)(lp), 16, 0, 0)

// ---------------------------------------------------------------------------
// Mask dtype detection: deterministic, graph-capture safe.
__global__ void detect_kernel(const unsigned char* __restrict__ m,
                              int* __restrict__ flag) {
    __shared__ int cnt;
    if (threadIdx.x == 0) cnt = 0;
    __syncthreads();
    int c = 0;
    for (int i = threadIdx.x; i < 16384; i += 256) {
        if ((i & 3) != 0 && m[i] != 0) c = 1;
    }
    if (c) atomicAdd(&cnt, 1);
    __syncthreads();
    if (threadIdx.x == 0) *flag = (cnt == 0) ? 1 : 0;
}

// ---------------------------------------------------------------------------
// Kernel 1: scores + masked exp + per-block denominator partials.
// Lane-split dot product: thread (r = tid>>3, c = tid&7) owns d-slice
// {32t + 4c .. +3} of FOUR K rows {bx*128 + 32j + r}. A wave's K loads are
// 8 x 128B contiguous segments (perfectly coalesced float4 straight to
// VGPRs) -- no LDS staging, no main-loop barriers, compiler pipelines
// freely. Q sits in LDS (staged once, linear); inner reads are
// 8-distinct-address broadcasts (conflict-free), amortized over 4 rows.
// Scores finished by a 3-step shfl_xor butterfly over the c-lanes.
__global__ __launch_bounds__(256, 2) void qk_softmax_kernel(
    const float* __restrict__ Qg, const float* __restrict__ Kg,
    const void* __restrict__ maskg, const int* __restrict__ flag,
    float* __restrict__ P, float* __restrict__ partial) {
    const int bx  = blockIdx.x;   // 0..31, chunk of 128 K-rows
    const int b   = blockIdx.y;   // 0..31
    const int tid = threadIdx.x;
    const int r   = tid >> 3;     // 0..31
    const int c   = tid & 7;      // 0..7

    __shared__ float qs[LQ * DD];   // 55,296 B
    __shared__ float part[4][LQ];

    // ---- stage Q[b] into LDS once, linear+coalesced, async ----
    {
        const float* Qb = Qg + (size_t)b * LQ * DD;
        for (int i = tid; i < (LQ * DD) / 4; i += 256)
            GLD16(Qb + i * 4, qs + i * 4);
    }
    asm volatile("s_waitcnt vmcnt(0)" ::: "memory");
    __syncthreads();

    float acc[4][LQ];
#pragma unroll
    for (int j = 0; j < 4; ++j)
#pragma unroll
        for (int q = 0; q < LQ; ++q) acc[j][q] = 0.0f;

    const float* K0 = Kg + ((size_t)b * LK + bx * 128 + r) * DD + (c << 2);

    for (int t = 0; t < DD / 32; ++t) {
        float4 kv[4];
#pragma unroll
        for (int j = 0; j < 4; ++j)
            kv[j] = *(const float4*)(K0 + (size_t)j * 32 * DD + t * 32);
#pragma unroll
        for (int q = 0; q < LQ; ++q) {
            const float4 qv = *(const float4*)(qs + q * DD + t * 32 + (c << 2));
#pragma unroll
            for (int j = 0; j < 4; ++j) {
                acc[j][q] += qv.x * kv[j].x;
                acc[j][q] += qv.y * kv[j].y;
                acc[j][q] += qv.z * kv[j].z;
                acc[j][q] += qv.w * kv[j].w;
            }
        }
    }

    // ---- butterfly over the 8 c-lanes: full dot in every lane ----
#pragma unroll
    for (int j = 0; j < 4; ++j)
#pragma unroll
        for (int q = 0; q < LQ; ++q) {
            float s = acc[j][q];
            s += __shfl_xor(s, 1, 64);
            s += __shfl_xor(s, 2, 64);
            s += __shfl_xor(s, 4, 64);
            acc[j][q] = s;
        }

    const int isI32 = *flag;
    const unsigned char* m8  = (const unsigned char*)maskg;
    const int*           m32 = (const int*)maskg;

    // lane c owns q in {c, c+8, c+16 (c<2)}; slot = q>>3 (all static indices)
    float dsum[3] = {0.0f, 0.0f, 0.0f};
#pragma unroll
    for (int q = 0; q < LQ; ++q) {
        if ((q & 7) == c) {
#pragma unroll
            for (int j = 0; j < 4; ++j) {
                const int    k   = bx * 128 + (j << 5) + r;
                const size_t idx = ((size_t)b * LQ + q) * LK + k;
                const int    msk = isI32 ? m32[idx] : (int)m8[idx];
                const float  pv  = msk ? 0.0f : __expf(acc[j][q] * SCALE);
                P[idx] = pv;
                dsum[q >> 3] += pv;
            }
        }
    }

    // reduce denominator over the 8 r-lanes of this wave (c preserved)
#pragma unroll
    for (int i = 0; i < 3; ++i) {
        float s = dsum[i];
        s += __shfl_xor(s, 8, 64);
        s += __shfl_xor(s, 16, 64);
        s += __shfl_xor(s, 32, 64);
        dsum[i] = s;
    }
    const int w = tid >> 6;
    if ((tid & 63) < 8) {              // one lane per (wave, c)
        part[w][c]     = dsum[0];
        part[w][c + 8] = dsum[1];
        if (c < 2) part[w][c + 16] = dsum[2];
    }
    __syncthreads();
    if (tid < LQ) {
        partial[((size_t)b * LQ + tid) * 32 + bx] =
            part[0][tid] + part[1][tid] + part[2][tid] + part[3][tid];
    }
}

// ---------------------------------------------------------------------------
// Kernel 2: reduce 32 per-block partials -> wqd[b][q] = W[q]/denom[b][q]
__global__ void denom_kernel(const float* __restrict__ partial,
                             const float* __restrict__ Wg,
                             float* __restrict__ wqd) {
    const int b = blockIdx.x;
    const int q = threadIdx.x;
    if (q < LQ) {
        const float* pp = partial + ((size_t)b * LQ + q) * 32;
        float s = 0.0f;
#pragma unroll
        for (int w = 0; w < 32; ++w) s += pp[w];
        wqd[b * LQ + q] = Wg[q] / s;
    }
}

// ---------------------------------------------------------------------------
// Kernel 3: attn_fc[b,k] = sum_q P[b,q,k]*wqd[b,q]; context[b,d] += af*V[b,k,d]
// Phase A: thread t <-> row k0+t (coalesced P reads), af -> LDS + d_out.
// Phase B: 192 lanes x float4 over d (one full 3KB V row per instruction).
__global__ __launch_bounds__(256, 2) void fc_context_kernel(
    const float* __restrict__ P, const float* __restrict__ Vg,
    const float* __restrict__ wqd, float* __restrict__ ctx_out,
    float* __restrict__ af_out) {
    const int chunk = blockIdx.x;   // 0..15
    const int b     = blockIdx.y;
    const int tid   = threadIdx.x;
    const int k0    = chunk * 256;

    __shared__ float af_s[256];

    {
        const int k = k0 + tid;
        float af = 0.0f;
#pragma unroll
        for (int q = 0; q < LQ; ++q) {
            af += P[((size_t)b * LQ + q) * LK + k] * wqd[b * LQ + q];
        }
        af_s[tid] = af;
        af_out[(size_t)b * LK + k] = af;
    }
    __syncthreads();

    if (tid < 192) {
        const int d = tid << 2;                 // 0..764, float4 per lane
        const float* Vb = Vg + ((size_t)b * LK + k0) * DD + d;
        float cx = 0.0f, cy = 0.0f, cz = 0.0f, cw = 0.0f;
#pragma unroll 8
        for (int j = 0; j < 256; ++j) {
            const float  a = af_s[j];
            const float4 v = *(const float4*)(Vb + (size_t)j * DD);
            cx += a * v.x;
            cy += a * v.y;
            cz += a * v.z;
            cw += a * v.w;
        }
        float* cp = ctx_out + b * DD + d;
        atomicAdd(cp + 0, cx);
        atomicAdd(cp + 1, cy);
        atomicAdd(cp + 2, cz);
        atomicAdd(cp + 3, cw);
    }
}

// ---------------------------------------------------------------------------
extern "C" void kernel_launch(void* const* d_in, const int* in_sizes, int n_in,
                              void* d_out, int out_size, void* d_ws, size_t ws_size,
                              hipStream_t stream) {
    const float* Qg   = (const float*)d_in[0];
    const float* Kg   = (const float*)d_in[1];
    const float* Vg   = (const float*)d_in[2];
    const void*  mask = d_in[3];
    const float* Wg   = (const float*)d_in[4];

    // outputs: context [32,1,768] then attn_fc [32,4096,1], both fp32
    float* ctx_out = (float*)d_out;
    float* af_out  = (float*)d_out + BB * DD;

    char*  ws      = (char*)d_ws;
    float* P       = (float*)(ws + WS_P);
    float* partial = (float*)(ws + WS_PARTIAL);
    float* wqd     = (float*)(ws + WS_WQD);
    int*   flag    = (int*)(ws + WS_FLAG);

    // context region accumulated via atomics -> zero it (memset node is
    // graph-capture safe). attn_fc region is fully overwritten, no memset.
    hipMemsetAsync(d_out, 0, BB * DD * sizeof(float), stream);

    detect_kernel<<<1, 256, 0, stream>>>((const unsigned char*)mask, flag);
    qk_softmax_kernel<<<dim3(32, BB), 256, 0, stream>>>(Qg, Kg, mask, flag, P, partial);
    denom_kernel<<<BB, 64, 0, stream>>>(partial, Wg, wqd);
    fc_context_kernel<<<dim3(16, BB), 256, 0, stream>>>(P, Vg, wqd, ctx_out, af_out);
}

// Round 4
// 832.093 us; speedup vs baseline: 1.0826x; 1.0272x over previous
//
#include <hip/hip_runtime.h>
#include <hip/hip_bf16.h>

// Problem constants
#define BB 32
#define LQ 18
#define LK 4096
#define DD 768
#define SCALE 0.03608439182435161f  // 1/sqrt(768)

// Workspace layout (bytes):
//   P       : [32][18][4096] fp32   @ 0        (9,437,184 B)
//   partial : [32][18][16]   fp32   @ 9437184  (36,864 B)   per-block denom partials
//   wqd     : [32][18]       fp32   @ 9510912  (2,304 B)    W[q]/denom[b][q]
//   flag    : int                   @ 9513216  (4 B)        mask dtype: 1=int32, 0=byte
#define WS_P       0
#define WS_PARTIAL 9437184
#define WS_WQD     9510912
#define WS_FLAG    9513216

// async global->LDS, 16B per lane (LDS dest = uniform base + lane*16, linear)
#define GLD16(gp, lp) __builtin_amdgcn_global_load_lds(                      \
    (const __attribute__((address_space(1))) void*)(gp),                     \
    (__attribute__((address_space(3))) void*)(lp), 16, 0, 0)

// ---------------------------------------------------------------------------
// Mask dtype detection: deterministic, graph-capture safe.
__global__ void detect_kernel(const unsigned char* __restrict__ m,
                              int* __restrict__ flag) {
    __shared__ int cnt;
    if (threadIdx.x == 0) cnt = 0;
    __syncthreads();
    int c = 0;
    for (int i = threadIdx.x; i < 16384; i += 256) {
        if ((i & 3) != 0 && m[i] != 0) c = 1;
    }
    if (c) atomicAdd(&cnt, 1);
    __syncthreads();
    if (threadIdx.x == 0) *flag = (cnt == 0) ? 1 : 0;
}

// ---------------------------------------------------------------------------
// Kernel 1: scores + masked exp + per-block denominator partials.
// 512-thread blocks: one 55KB Q-in-LDS copy now serves 8 waves, so the
// 2-blocks/CU LDS limit gives 4 waves/SIMD (was 2) -> latency hiding for
// the K stream without any main-loop barriers or staging.
// Thread (r = tid>>3, c = tid&7) owns d-slice {32t + 4c .. +3} of FOUR
// K rows {bx*256 + 64j + r}; a wave's K loads are 8 x 128B contiguous
// segments (coalesced float4 straight to VGPRs). Q reads from LDS are
// 8-distinct-address broadcasts (conflict-free), amortized over 4 rows.
// Scores finished by a 3-step shfl_xor butterfly over the c-lanes.
__global__ __launch_bounds__(512, 4) void qk_softmax_kernel(
    const float* __restrict__ Qg, const float* __restrict__ Kg,
    const void* __restrict__ maskg, const int* __restrict__ flag,
    float* __restrict__ P, float* __restrict__ partial) {
    const int bx  = blockIdx.x;   // 0..15, chunk of 256 K-rows
    const int b   = blockIdx.y;   // 0..31
    const int tid = threadIdx.x;
    const int r   = tid >> 3;     // 0..63
    const int c   = tid & 7;      // 0..7

    __shared__ float qs[LQ * DD];   // 55,296 B
    __shared__ float part[8][LQ];

    // ---- stage Q[b] into LDS once, linear+coalesced, async ----
    {
        const float* Qb = Qg + (size_t)b * LQ * DD;
        for (int i = tid; i < (LQ * DD) / 4; i += 512)
            GLD16(Qb + i * 4, qs + i * 4);
    }
    asm volatile("s_waitcnt vmcnt(0)" ::: "memory");
    __syncthreads();

    float acc[4][LQ];
#pragma unroll
    for (int j = 0; j < 4; ++j)
#pragma unroll
        for (int q = 0; q < LQ; ++q) acc[j][q] = 0.0f;

    const float* K0 = Kg + ((size_t)b * LK + bx * 256 + r) * DD + (c << 2);

    for (int t = 0; t < DD / 32; ++t) {
        float4 kv[4];
#pragma unroll
        for (int j = 0; j < 4; ++j)
            kv[j] = *(const float4*)(K0 + (size_t)j * 64 * DD + t * 32);
#pragma unroll
        for (int q = 0; q < LQ; ++q) {
            const float4 qv = *(const float4*)(qs + q * DD + t * 32 + (c << 2));
#pragma unroll
            for (int j = 0; j < 4; ++j) {
                acc[j][q] += qv.x * kv[j].x;
                acc[j][q] += qv.y * kv[j].y;
                acc[j][q] += qv.z * kv[j].z;
                acc[j][q] += qv.w * kv[j].w;
            }
        }
    }

    // ---- butterfly over the 8 c-lanes: full dot in every lane ----
#pragma unroll
    for (int j = 0; j < 4; ++j)
#pragma unroll
        for (int q = 0; q < LQ; ++q) {
            float s = acc[j][q];
            s += __shfl_xor(s, 1, 64);
            s += __shfl_xor(s, 2, 64);
            s += __shfl_xor(s, 4, 64);
            acc[j][q] = s;
        }

    const int isI32 = *flag;
    const unsigned char* m8  = (const unsigned char*)maskg;
    const int*           m32 = (const int*)maskg;

    // lane c owns q in {c, c+8, c+16 (c<2)}; slot = q>>3 (all static indices)
    float dsum[3] = {0.0f, 0.0f, 0.0f};
#pragma unroll
    for (int q = 0; q < LQ; ++q) {
        if ((q & 7) == c) {
#pragma unroll
            for (int j = 0; j < 4; ++j) {
                const int    k   = bx * 256 + (j << 6) + r;
                const size_t idx = ((size_t)b * LQ + q) * LK + k;
                const int    msk = isI32 ? m32[idx] : (int)m8[idx];
                const float  pv  = msk ? 0.0f : __expf(acc[j][q] * SCALE);
                P[idx] = pv;
                dsum[q >> 3] += pv;
            }
        }
    }

    // reduce denominator over the 8 r-lanes of this wave (c preserved)
#pragma unroll
    for (int i = 0; i < 3; ++i) {
        float s = dsum[i];
        s += __shfl_xor(s, 8, 64);
        s += __shfl_xor(s, 16, 64);
        s += __shfl_xor(s, 32, 64);
        dsum[i] = s;
    }
    const int w = tid >> 6;            // wave id 0..7
    if ((tid & 63) < 8) {              // one lane per (wave, c)
        part[w][c]     = dsum[0];
        part[w][c + 8] = dsum[1];
        if (c < 2) part[w][c + 16] = dsum[2];
    }
    __syncthreads();
    if (tid < LQ) {
        float s = 0.0f;
#pragma unroll
        for (int w2 = 0; w2 < 8; ++w2) s += part[w2][tid];
        partial[((size_t)b * LQ + tid) * 16 + bx] = s;
    }
}

// ---------------------------------------------------------------------------
// Kernel 2: reduce 16 per-block partials -> wqd[b][q] = W[q]/denom[b][q]
__global__ void denom_kernel(const float* __restrict__ partial,
                             const float* __restrict__ Wg,
                             float* __restrict__ wqd) {
    const int b = blockIdx.x;
    const int q = threadIdx.x;
    if (q < LQ) {
        const float* pp = partial + ((size_t)b * LQ + q) * 16;
        float s = 0.0f;
#pragma unroll
        for (int w = 0; w < 16; ++w) s += pp[w];
        wqd[b * LQ + q] = Wg[q] / s;
    }
}

// ---------------------------------------------------------------------------
// Kernel 3: attn_fc[b,k] = sum_q P[b,q,k]*wqd[b,q]; context[b,d] += af*V[b,k,d]
// Phase A: thread t <-> row k0+t (coalesced P reads), af -> LDS + d_out.
// Phase B: 192 lanes x float4 over d (one full 3KB V row per instruction).
__global__ __launch_bounds__(256, 2) void fc_context_kernel(
    const float* __restrict__ P, const float* __restrict__ Vg,
    const float* __restrict__ wqd, float* __restrict__ ctx_out,
    float* __restrict__ af_out) {
    const int chunk = blockIdx.x;   // 0..15
    const int b     = blockIdx.y;
    const int tid   = threadIdx.x;
    const int k0    = chunk * 256;

    __shared__ float af_s[256];

    {
        const int k = k0 + tid;
        float af = 0.0f;
#pragma unroll
        for (int q = 0; q < LQ; ++q) {
            af += P[((size_t)b * LQ + q) * LK + k] * wqd[b * LQ + q];
        }
        af_s[tid] = af;
        af_out[(size_t)b * LK + k] = af;
    }
    __syncthreads();

    if (tid < 192) {
        const int d = tid << 2;                 // 0..764, float4 per lane
        const float* Vb = Vg + ((size_t)b * LK + k0) * DD + d;
        float cx = 0.0f, cy = 0.0f, cz = 0.0f, cw = 0.0f;
#pragma unroll 8
        for (int j = 0; j < 256; ++j) {
            const float  a = af_s[j];
            const float4 v = *(const float4*)(Vb + (size_t)j * DD);
            cx += a * v.x;
            cy += a * v.y;
            cz += a * v.z;
            cw += a * v.w;
        }
        float* cp = ctx_out + b * DD + d;
        atomicAdd(cp + 0, cx);
        atomicAdd(cp + 1, cy);
        atomicAdd(cp + 2, cz);
        atomicAdd(cp + 3, cw);
    }
}

// ---------------------------------------------------------------------------
extern "C" void kernel_launch(void* const* d_in, const int* in_sizes, int n_in,
                              void* d_out, int out_size, void* d_ws, size_t ws_size,
                              hipStream_t stream) {
    const float* Qg   = (const float*)d_in[0];
    const float* Kg   = (const float*)d_in[1];
    const float* Vg   = (const float*)d_in[2];
    const void*  mask = d_in[3];
    const float* Wg   = (const float*)d_in[4];

    // outputs: context [32,1,768] then attn_fc [32,4096,1], both fp32
    float* ctx_out = (float*)d_out;
    float* af_out  = (float*)d_out + BB * DD;

    char*  ws      = (char*)d_ws;
    float* P       = (float*)(ws + WS_P);
    float* partial = (float*)(ws + WS_PARTIAL);
    float* wqd     = (float*)(ws + WS_WQD);
    int*   flag    = (int*)(ws + WS_FLAG);

    // context region accumulated via atomics -> zero it (memset node is
    // graph-capture safe). attn_fc region is fully overwritten, no memset.
    hipMemsetAsync(d_out, 0, BB * DD * sizeof(float), stream);

    detect_kernel<<<1, 256, 0, stream>>>((const unsigned char*)mask, flag);
    qk_softmax_kernel<<<dim3(16, BB), 512, 0, stream>>>(Qg, Kg, mask, flag, P, partial);
    denom_kernel<<<BB, 64, 0, stream>>>(partial, Wg, wqd);
    fc_context_kernel<<<dim3(16, BB), 256, 0, stream>>>(P, Vg, wqd, ctx_out, af_out);
}